// Round 17
// baseline (2707.979 us; speedup 1.0000x reference)
//
#include <hip/hip_runtime.h>

// WeightedRGCN on MI355X. Round 17: MFMA k-loop inside the PROVEN R16
// structure (separate kernels, 2 blocks/CU) — not R11's fused mega-kernel.
// R16 counters: fp32 k-loop is the cost (VALUBusy 56%, ~10% of fp32 peak on
// 26 GFLOP). MFMA pieces are R11-verified (passed 0.0625); gather is R16's
// verified interleaved float2 (features 2*lane,2*lane+1 -> matching slots).
//
// ws layout (words), ~14.8M = 59.2 MB:
//   [0 .. 12.8M)     uacc (fp32 user accumulator)
//   [12.8M .. +1.6M) col_idx  [.. +200001) row_ptr  [.. +200K) wcur

#define N_USER 100000
#define N_POST 200000
#define DD 128
#define E_MAX 1600000

typedef __attribute__((ext_vector_type(8))) short short8;
typedef __attribute__((ext_vector_type(4))) float floatx4;

__device__ __forceinline__ unsigned int pack2_bf16(float lo, float hi) {
    unsigned int ulo, uhi;
    __builtin_memcpy(&ulo, &lo, 4);
    __builtin_memcpy(&uhi, &hi, 4);
    unsigned int rlo = (ulo + 0x7fffu + ((ulo >> 16) & 1u)) >> 16;   // RNE
    unsigned int rhi = (uhi + 0x7fffu + ((uhi >> 16) & 1u)) >> 16;
    return (rlo & 0xffffu) | (rhi << 16);
}

// -------------------------------------------------- CSR build (R10 verbatim)
__global__ __launch_bounds__(256) void csr_hist(
        const int* __restrict__ dst, int E, int* __restrict__ cnt) {
    int i = blockIdx.x * 256 + threadIdx.x;
    int stride = gridDim.x * 256;
    for (int e = i; e < E; e += stride) atomicAdd(&cnt[dst[e]], 1);
}

#define SCAN_T 1024
#define SCAN_EPT 8
__global__ __launch_bounds__(SCAN_T) void scan_excl(int* __restrict__ a, int N) {
    __shared__ int tsum[SCAN_T];
    __shared__ int carry_s;
    int tid = threadIdx.x;
    if (tid == 0) carry_s = 0;
    __syncthreads();
    const int CH = SCAN_T * SCAN_EPT;
    for (int base = 0; base < N; base += CH) {
        int v[SCAN_EPT];
        int mysum = 0;
        int i0 = base + tid * SCAN_EPT;
#pragma unroll
        for (int j = 0; j < SCAN_EPT; ++j) {
            int i = i0 + j;
            v[j] = (i < N) ? a[i] : 0;
            mysum += v[j];
        }
        tsum[tid] = mysum;
        __syncthreads();
        for (int off = 1; off < SCAN_T; off <<= 1) {
            int t = (tid >= off) ? tsum[tid - off] : 0;
            __syncthreads();
            tsum[tid] += t;
            __syncthreads();
        }
        int carry = carry_s;
        int run = carry + tsum[tid] - mysum;
#pragma unroll
        for (int j = 0; j < SCAN_EPT; ++j) {
            int i = i0 + j;
            if (i < N) a[i] = run;
            run += v[j];
        }
        __syncthreads();
        if (tid == SCAN_T - 1) carry_s = carry + tsum[tid];
        __syncthreads();
    }
    if (tid == 0) a[N] = carry_s;
}

__global__ __launch_bounds__(256) void csr_fill(
        const int* __restrict__ src, const int* __restrict__ dst, int E,
        const int* __restrict__ rp, int* __restrict__ wcur, int* __restrict__ col) {
    int i = blockIdx.x * 256 + threadIdx.x;
    int stride = gridDim.x * 256;
    for (int e = i; e < E; e += stride) {
        int d = dst[e];
        int pos = rp[d] + atomicAdd(&wcur[d], 1);
        col[pos] = src[e];
    }
}

// ------------------------------------------------------- MFMA pieces (R11) --
// Bt[col][k2] bf16x2 words, XOR-swizzled: Bt[c*64 + (k2 ^ ((c&7)<<2))]
__device__ __forceinline__ void stage_Bt_one(const float* __restrict__ W,
                                             int* Bt, int tid) {
    for (int idx = tid; idx < 128 * 64; idx += 512) {
        int c = idx & 127, k2 = idx >> 7;
        float lo = W[(2 * k2) * 128 + c];
        float hi = W[(2 * k2 + 1) * 128 + c];
        Bt[c * 64 + (k2 ^ ((c & 7) << 2))] = pack2_bf16(lo, hi);
    }
}
__device__ __forceinline__ void stage_Bt_comb(const float* __restrict__ W0,
                                              const float* __restrict__ W1,
                                              const float* __restrict__ W2,
                                              int* Bt, int tid) {
    for (int idx = tid; idx < 128 * 64; idx += 512) {
        int c = idx & 127, k2 = idx >> 7;
        int e0 = (2 * k2) * 128 + c, e1 = (2 * k2 + 1) * 128 + c;
        float lo = 1.75f * W0[e0] + 0.7f * W1[e0] + 0.3f * W2[e0];
        float hi = 1.75f * W0[e1] + 0.7f * W1[e1] + 0.3f * W2[e1];
        Bt[c * 64 + (k2 ^ ((c & 7) << 2))] = pack2_bf16(lo, hi);
    }
}

// dense 16 rows -> per-wave A tile (R11 verbatim, verified)
__device__ __forceinline__ void dense_A(const float* __restrict__ x,
                                        int rowbase, int N, int lane, int* Aw) {
    for (int i = 0; i < 16; ++i) {
        int row = rowbase + i;
        float vx = 0.f, vy = 0.f;
        if (row < N) {
            float2 v = ((const float2*)(x + (size_t)row * DD))[lane];
            vx = v.x; vy = v.y;
        }
        Aw[i * 64 + (lane ^ ((i & 7) << 2))] = pack2_bf16(vx, vy);
    }
}

// CSR-mean 16 rows: 4 groups of 4-row INTERLEAVED edge loops (R16-verified
// mapping: float2 gives features 2*lane,2*lane+1 -> word slot `lane`).
__device__ __forceinline__ void gather_A_ilp(const float* __restrict__ x,
                                             const int* __restrict__ rp,
                                             const int* __restrict__ col, float scale,
                                             int rowbase, int N, int lane, int* Aw) {
#pragma unroll
    for (int g = 0; g < 4; ++g) {
        int s0[4], dg[4];
        int maxd = 0;
#pragma unroll
        for (int i = 0; i < 4; ++i) {
            int row = rowbase + g * 4 + i;
            int e0 = (row < N) ? rp[row] : 0;
            int e1 = (row < N) ? rp[row + 1] : 0;
            s0[i] = e0;
            dg[i] = e1 - e0;
            maxd = max(maxd, dg[i]);
        }
        float a0[4] = {0.f, 0.f, 0.f, 0.f};
        float a1[4] = {0.f, 0.f, 0.f, 0.f};
#pragma unroll 2
        for (int d = 0; d < maxd; ++d) {
#pragma unroll
            for (int i = 0; i < 4; ++i) {
                if (d < dg[i]) {
                    float2 v = ((const float2*)(x + (size_t)col[s0[i] + d] * DD))[lane];
                    a0[i] += v.x;
                    a1[i] += v.y;
                }
            }
        }
#pragma unroll
        for (int i = 0; i < 4; ++i) {
            int r = g * 4 + i;
            float inv = scale / fmaxf((float)dg[i], 1.0f);
            Aw[r * 64 + (lane ^ ((r & 7) << 2))] = pack2_bf16(a0[i] * inv, a1[i] * inv);
        }
    }
}

// 32 MFMA: 8 col-tiles x 4 K-steps (R11 verbatim, verified)
__device__ __forceinline__ void kloop_mfma(const int* Aw, const int* Bt,
                                           int lane, floatx4 acc[8]) {
    int r16 = lane & 15, h = lane >> 4;
    int sw = (r16 & 7) << 4;
#pragma unroll
    for (int ks = 0; ks < 4; ++ks) {
        int off = (ks * 64 + h * 16) ^ sw;
        short8 a = *(const short8*)((const char*)Aw + r16 * 256 + off);
#pragma unroll
        for (int ct = 0; ct < 8; ++ct) {
            short8 b = *(const short8*)((const char*)Bt + (r16 + ct * 16) * 256 + off);
            acc[ct] = __builtin_amdgcn_mfma_f32_16x16x32_bf16(a, b, acc[ct], 0, 0, 0);
        }
    }
}

// ---------------------------------------------------------------- kernels ---
// uacc += scale * csr_mean(x) @ B
__global__ __launch_bounds__(512) void pull_gemm_mfma(
        const float* __restrict__ x, const int* __restrict__ rp,
        const int* __restrict__ col, const float* __restrict__ B,
        float scale, float* __restrict__ Y, int N) {
    __shared__ int Bt[128 * 64];
    __shared__ int Als[8][16 * 64];
    int tid = threadIdx.x, wave = tid >> 6, lane = tid & 63;
    stage_Bt_one(B, Bt, tid);                 // staging hides under gather
    int rb = blockIdx.x * 128 + wave * 16;
    floatx4 zz = {0.f, 0.f, 0.f, 0.f};
    floatx4 acc[8];
#pragma unroll
    for (int ct = 0; ct < 8; ++ct) acc[ct] = zz;
    gather_A_ilp(x, rp, col, scale, rb, N, lane, Als[wave]);
    __syncthreads();
    kloop_mfma(Als[wave], Bt, lane, acc);
    int r16 = lane & 15, h = lane >> 4;
#pragma unroll
    for (int ct = 0; ct < 8; ++ct) {
        int c = ct * 16 + r16;
#pragma unroll
        for (int r = 0; r < 4; ++r) {
            int row = rb + h * 4 + r;
            if (row < N) Y[(size_t)row * DD + c] += acc[ct][r];
        }
    }
}

// out_user = relu(uacc + xu @ (1.75WrD+0.7WrA+0.3WrS) + b_comb)
__global__ __launch_bounds__(512) void user_final_mfma(
        const float* __restrict__ uacc, const float* __restrict__ xu,
        const float* __restrict__ WrD, const float* __restrict__ WrA,
        const float* __restrict__ WrS, const float* __restrict__ bD,
        const float* __restrict__ bA, const float* __restrict__ bS,
        float* __restrict__ out) {
    __shared__ int Bt[128 * 64];
    __shared__ int Als[8][16 * 64];
    __shared__ float bcs[128];
    int tid = threadIdx.x, wave = tid >> 6, lane = tid & 63;
    stage_Bt_comb(WrD, WrA, WrS, Bt, tid);
    if (tid < 128) bcs[tid] = 1.75f * bD[tid] + 0.7f * bA[tid] + 0.3f * bS[tid];
    int rb = blockIdx.x * 128 + wave * 16;
    floatx4 zz = {0.f, 0.f, 0.f, 0.f};
    floatx4 acc[8];
#pragma unroll
    for (int ct = 0; ct < 8; ++ct) acc[ct] = zz;
    dense_A(xu, rb, N_USER, lane, Als[wave]);
    __syncthreads();
    kloop_mfma(Als[wave], Bt, lane, acc);
    int r16 = lane & 15, h = lane >> 4;
#pragma unroll
    for (int ct = 0; ct < 8; ++ct) {
        int c = ct * 16 + r16;
        float bc = bcs[c];
#pragma unroll
        for (int r = 0; r < 4; ++r) {
            int row = rb + h * 4 + r;
            if (row < N_USER)
                out[(size_t)row * DD + c] =
                    fmaxf(uacc[(size_t)row * DD + c] + acc[ct][r] + bc, 0.f);
        }
    }
}

// out_post = relu(csr_mean(xu)@Wl + xp@Wr + b); two staged passes.
__global__ __launch_bounds__(512) void post_final_mfma(
        const float* __restrict__ xu, const int* __restrict__ rp,
        const int* __restrict__ col, const float* __restrict__ xp,
        const float* __restrict__ Wl, const float* __restrict__ Wr,
        const float* __restrict__ bias, float* __restrict__ out) {
    __shared__ int Bt[128 * 64];
    __shared__ int Als[8][16 * 64];
    __shared__ float bcs[128];
    int tid = threadIdx.x, wave = tid >> 6, lane = tid & 63;
    if (tid < 128) bcs[tid] = bias[tid];
    int rb = blockIdx.x * 128 + wave * 16;
    floatx4 zz = {0.f, 0.f, 0.f, 0.f};
    floatx4 acc[8];
#pragma unroll
    for (int ct = 0; ct < 8; ++ct) acc[ct] = zz;
    // pass 1: gather(eng) @ Wl
    stage_Bt_one(Wl, Bt, tid);
    gather_A_ilp(xu, rp, col, 1.0f, rb, N_POST, lane, Als[wave]);
    __syncthreads();
    kloop_mfma(Als[wave], Bt, lane, acc);
    __syncthreads();               // all waves done reading Bt(Wl)
    // pass 2: dense xp @ Wr
    stage_Bt_one(Wr, Bt, tid);
    dense_A(xp, rb, N_POST, lane, Als[wave]);
    __syncthreads();
    kloop_mfma(Als[wave], Bt, lane, acc);
    int r16 = lane & 15, h = lane >> 4;
#pragma unroll
    for (int ct = 0; ct < 8; ++ct) {
        int c = ct * 16 + r16;
        float bc = bcs[c];
#pragma unroll
        for (int r = 0; r < 4; ++r) {
            int row = rb + h * 4 + r;
            if (row < N_POST)
                out[(size_t)row * DD + c] = fmaxf(acc[ct][r] + bc, 0.f);
        }
    }
}

// ------------------------------------------------------------------ launch --
extern "C" void kernel_launch(void* const* d_in, const int* in_sizes, int n_in,
                              void* d_out, int out_size, void* d_ws, size_t ws_size,
                              hipStream_t stream) {
    const float* x_user  = (const float*)d_in[0];
    const float* x_post  = (const float*)d_in[1];
    const int*   re_src  = (const int*)d_in[2];
    const int*   re_dst  = (const int*)d_in[3];
    const int*   fb_src  = (const int*)d_in[4];
    const int*   fb_dst  = (const int*)d_in[5];
    const int*   soc_src = (const int*)d_in[6];
    const int*   soc_dst = (const int*)d_in[7];
    const int*   eng_src = (const int*)d_in[8];
    const int*   eng_dst = (const int*)d_in[9];
    const float* Wl_d = (const float*)d_in[10];
    const float* bl_d = (const float*)d_in[11];
    const float* Wr_d = (const float*)d_in[12];
    const float* Wl_a = (const float*)d_in[13];
    const float* bl_a = (const float*)d_in[14];
    const float* Wr_a = (const float*)d_in[15];
    const float* Wl_s = (const float*)d_in[16];
    const float* bl_s = (const float*)d_in[17];
    const float* Wr_s = (const float*)d_in[18];
    const float* Wl_p = (const float*)d_in[19];
    const float* bl_p = (const float*)d_in[20];
    const float* Wr_p = (const float*)d_in[21];

    const int E_re  = in_sizes[2];
    const int E_fb  = in_sizes[4];
    const int E_soc = in_sizes[6];
    const int E_eng = in_sizes[8];

    float* uacc    = (float*)d_ws;                               // 12.8M floats
    int*   col_idx = (int*)((float*)d_ws + (size_t)N_USER * DD); // 1.6M ints
    int*   row_ptr = col_idx + E_MAX;                            // 200001 ints
    int*   wcur    = row_ptr + (N_POST + 1);                     // 200000 ints

    float* out_user = (float*)d_out;
    float* out_post = out_user + (size_t)N_USER * DD;

    const int gU = (N_USER + 127) / 128;   // 782 blocks * 8 waves * 16 rows
    const int gP = (N_POST + 127) / 128;   // 1563

    auto build_csr = [&](const int* src, const int* dst, int E, int Ndst) {
        hipMemsetAsync(row_ptr, 0, (Ndst + 1) * sizeof(int), stream);
        hipMemsetAsync(wcur, 0, Ndst * sizeof(int), stream);
        csr_hist<<<1024, 256, 0, stream>>>(dst, E, row_ptr);
        scan_excl<<<1, SCAN_T, 0, stream>>>(row_ptr, Ndst);
        csr_fill<<<1024, 256, 0, stream>>>(src, dst, E, row_ptr, wcur, col_idx);
    };

    hipMemsetAsync(uacc, 0, (size_t)N_USER * DD * sizeof(float), stream);

    // ---- user: direct (re: post -> user) ----
    build_csr(re_src, re_dst, E_re, N_USER);
    pull_gemm_mfma<<<gU, 512, 0, stream>>>(x_post, row_ptr, col_idx, Wl_d, 1.75f, uacc, N_USER);

    // ---- user: author (fb: post -> user) ----
    build_csr(fb_src, fb_dst, E_fb, N_USER);
    pull_gemm_mfma<<<gU, 512, 0, stream>>>(x_post, row_ptr, col_idx, Wl_a, 0.7f, uacc, N_USER);

    // ---- user: social (soc: user -> user) ----
    build_csr(soc_src, soc_dst, E_soc, N_USER);
    pull_gemm_mfma<<<gU, 512, 0, stream>>>(x_user, row_ptr, col_idx, Wl_s, 0.3f, uacc, N_USER);

    // ---- user output ----
    user_final_mfma<<<gU, 512, 0, stream>>>(uacc, x_user, Wr_d, Wr_a, Wr_s,
                                            bl_d, bl_a, bl_s, out_user);

    // ---- post: eng (user -> post) ----
    build_csr(eng_src, eng_dst, E_eng, N_POST);
    post_final_mfma<<<gP, 512, 0, stream>>>(x_user, row_ptr, col_idx, x_post,
                                            Wl_p, Wr_p, bl_p, out_post);
}

// Round 18
// 1737.002 us; speedup vs baseline: 1.5590x; 1.5590x over previous
//
#include <hip/hip_runtime.h>

// WeightedRGCN on MI355X. Round 18: revert R17's MFMA (occupancy regression:
// 63%->21%, gather-latency-bound workload needs waves). Base = proven R16
// (2317us, fp32 kloop, 40 VGPR, 48KB LDS, 3 blocks/CU) plus:
//  1. two-level scan (EXONERATED by R13/R14 bisect; replaces 4x single-block
//     scan_excl ~50-100us each)
//  2. user path fused into ONE 4-phase kernel (exact post_final 2-pass
//     pattern x4): kills uacc (memset+3x RMW ~150us) + 3 launches.
// Failure localization: Output1 wrong => scan; Output0-only => fusion.
//
// ws layout (ints), ~6.3M = 25MB: rp_re/rp_fb/rp_soc (N_USER+1 each),
// rp_post (N_POST+1), wcur (N_POST), psum (64), col_re/fb/soc/post (E each).

#define N_USER 100000
#define N_POST 200000
#define DD 128

__device__ __forceinline__ unsigned int pack2_bf16(float lo, float hi) {
    unsigned int ulo, uhi;
    __builtin_memcpy(&ulo, &lo, 4);
    __builtin_memcpy(&uhi, &hi, 4);
    unsigned int rlo = (ulo + 0x7fffu + ((ulo >> 16) & 1u)) >> 16;   // RNE
    unsigned int rhi = (uhi + 0x7fffu + ((uhi >> 16) & 1u)) >> 16;
    return (rlo & 0xffffu) | (rhi << 16);
}
__device__ __forceinline__ float bf16_lo(unsigned int u) {
    unsigned int t = u << 16; float f; __builtin_memcpy(&f, &t, 4); return f;
}
__device__ __forceinline__ float bf16_hi(unsigned int u) {
    unsigned int t = u & 0xffff0000u; float f; __builtin_memcpy(&f, &t, 4); return f;
}

// -------------------------------------------------------------- CSR build ---
__global__ __launch_bounds__(256) void csr_hist(
        const int* __restrict__ dst, int E, int* __restrict__ cnt) {
    int i = blockIdx.x * 256 + threadIdx.x;
    int stride = gridDim.x * 256;
    for (int e = i; e < E; e += stride) atomicAdd(&cnt[dst[e]], 1);
}

// two-level exclusive scan (exonerated by R13/R14 bisect; re-reviewed)
#define SCB 256
#define SCE 16
#define SCCH (SCB * SCE)   // 4096 elems per block

__global__ __launch_bounds__(SCB) void scan_partial(
        const int* __restrict__ a, int N, int* __restrict__ psum) {
    __shared__ int red[SCB];
    int b = blockIdx.x, tid = threadIdx.x;
    int i0 = b * SCCH + tid * SCE;
    int s = 0;
#pragma unroll
    for (int j = 0; j < SCE; ++j) { int i = i0 + j; if (i < N) s += a[i]; }
    red[tid] = s;
    __syncthreads();
    for (int off = SCB / 2; off > 0; off >>= 1) {
        if (tid < off) red[tid] += red[tid + off];
        __syncthreads();
    }
    if (tid == 0) psum[b] = red[0];
}

__global__ __launch_bounds__(1024) void scan_psum(int* __restrict__ psum, int nb) {
    __shared__ int t[1024];
    int tid = threadIdx.x;
    int v = (tid < nb) ? psum[tid] : 0;
    t[tid] = v;
    __syncthreads();
    for (int off = 1; off < 1024; off <<= 1) {
        int u = (tid >= off) ? t[tid - off] : 0;
        __syncthreads();
        t[tid] += u;
        __syncthreads();
    }
    if (tid < nb) psum[tid] = t[tid] - v;   // exclusive
}

__global__ __launch_bounds__(SCB) void scan_final(
        int* __restrict__ a, int N, const int* __restrict__ psum, int E) {
    __shared__ int red[SCB];
    int b = blockIdx.x, tid = threadIdx.x;
    int i0 = b * SCCH + tid * SCE;
    int v[SCE];
    int s = 0;
#pragma unroll
    for (int j = 0; j < SCE; ++j) { int i = i0 + j; v[j] = (i < N) ? a[i] : 0; s += v[j]; }
    red[tid] = s;
    __syncthreads();
    for (int off = 1; off < SCB; off <<= 1) {   // inclusive Hillis-Steele
        int u = (tid >= off) ? red[tid - off] : 0;
        __syncthreads();
        red[tid] += u;
        __syncthreads();
    }
    int run = psum[b] + red[tid] - s;           // exclusive prefix for thread
#pragma unroll
    for (int j = 0; j < SCE; ++j) { int i = i0 + j; if (i < N) a[i] = run; run += v[j]; }
    if (b == 0 && tid == 0) a[N] = E;
}

__global__ __launch_bounds__(256) void csr_fill(
        const int* __restrict__ src, const int* __restrict__ dst, int E,
        const int* __restrict__ rp, int* __restrict__ wcur, int* __restrict__ col) {
    int i = blockIdx.x * 256 + threadIdx.x;
    int stride = gridDim.x * 256;
    for (int e = i; e < E; e += stride) {
        int d = dst[e];
        int pos = rp[d] + atomicAdd(&wcur[d], 1);
        col[pos] = src[e];
    }
}

// ------------------------------------------------- GEMM pieces (R16 proven) --
__device__ __forceinline__ void stage_B(const float* __restrict__ B,
                                        unsigned int* Bp, int tid) {
    for (int i = tid; i < 128 * 64; i += 512) {
        int k = i >> 6, j = i & 63;
        Bp[i] = pack2_bf16(B[k * 128 + j], B[k * 128 + j + 64]);
    }
}
__device__ __forceinline__ void stage_B_comb(const float* __restrict__ W0,
                                             const float* __restrict__ W1,
                                             const float* __restrict__ W2,
                                             unsigned int* Bp, int tid) {
    for (int i = tid; i < 128 * 64; i += 512) {
        int k = i >> 6, j = i & 63;
        float lo = 1.75f * W0[k*128+j]    + 0.7f * W1[k*128+j]    + 0.3f * W2[k*128+j];
        float hi = 1.75f * W0[k*128+j+64] + 0.7f * W1[k*128+j+64] + 0.3f * W2[k*128+j+64];
        Bp[i] = pack2_bf16(lo, hi);
    }
}

__device__ __forceinline__ void load_rows(const float* __restrict__ A,
                                          int base, int N, int lane, float* at) {
#pragma unroll
    for (int i = 0; i < 4; ++i) {
        int row = base + i;
        float a0 = 0.f, a1 = 0.f;
        if (row < N) {
            a0 = A[(size_t)row * DD + lane];
            a1 = A[(size_t)row * DD + 64 + lane];
        }
        at[lane * 4 + i] = a0;
        at[(lane + 64) * 4 + i] = a1;
    }
}

// R16-verified interleaved gather (float2 -> slots 2*lane, 2*lane+1)
__device__ __forceinline__ void gather_rows(const float* __restrict__ x,
                                            const int* __restrict__ rp,
                                            const int* __restrict__ col, float scale,
                                            int base, int N, int lane, float* at) {
    int s0[4], dg[4];
    int maxd = 0;
#pragma unroll
    for (int i = 0; i < 4; ++i) {
        int row = base + i;
        int e0 = (row < N) ? rp[row] : 0;
        int e1 = (row < N) ? rp[row + 1] : 0;
        s0[i] = e0;
        dg[i] = e1 - e0;
        maxd = max(maxd, dg[i]);
    }
    float a0[4] = {0.f, 0.f, 0.f, 0.f};
    float a1[4] = {0.f, 0.f, 0.f, 0.f};
#pragma unroll 2
    for (int d = 0; d < maxd; ++d) {
#pragma unroll
        for (int i = 0; i < 4; ++i) {
            if (d < dg[i]) {
                const float2* xr = (const float2*)(x + (size_t)col[s0[i] + d] * DD);
                float2 v = xr[lane];
                a0[i] += v.x;
                a1[i] += v.y;
            }
        }
    }
#pragma unroll
    for (int i = 0; i < 4; ++i) {
        float inv = scale / fmaxf((float)dg[i], 1.0f);
        at[(2 * lane) * 4 + i]     = a0[i] * inv;   // feature 2*lane
        at[(2 * lane + 1) * 4 + i] = a1[i] * inv;   // feature 2*lane+1
    }
}

// unroll 4 (NOT full): full unroll spills under the 128-VGPR cap (R5 35GB).
__device__ __forceinline__ void kloop_acc(const float* at, const unsigned int* Bp,
                                          int lane, float acc[4][2]) {
#pragma unroll 4
    for (int k = 0; k < 128; ++k) {
        float4 x = *reinterpret_cast<const float4*>(at + k * 4);
        unsigned int u = Bp[k * 64 + lane];
        float b0 = bf16_lo(u), b1 = bf16_hi(u);
        acc[0][0] = fmaf(x.x, b0, acc[0][0]); acc[0][1] = fmaf(x.x, b1, acc[0][1]);
        acc[1][0] = fmaf(x.y, b0, acc[1][0]); acc[1][1] = fmaf(x.y, b1, acc[1][1]);
        acc[2][0] = fmaf(x.z, b0, acc[2][0]); acc[2][1] = fmaf(x.z, b1, acc[2][1]);
        acc[3][0] = fmaf(x.w, b0, acc[3][0]); acc[3][1] = fmaf(x.w, b1, acc[3][1]);
    }
}

// ---------------------------------------------------------------- kernels ---
// out_user = relu( 1.75*mean_re(xp)@Wl_d + 0.7*mean_fb(xp)@Wl_a
//                + 0.3*mean_soc(xu)@Wl_s + xu@(1.75WrD+0.7WrA+0.3WrS) + bc )
// 4 phases, each = proven post_final pass pattern. No uacc.
__global__ __launch_bounds__(512) void user_fused_kernel(
        const float* __restrict__ xu, const float* __restrict__ xp,
        const int* __restrict__ rp_re, const int* __restrict__ col_re,
        const int* __restrict__ rp_fb, const int* __restrict__ col_fb,
        const int* __restrict__ rp_soc, const int* __restrict__ col_soc,
        const float* __restrict__ Wl_d, const float* __restrict__ Wl_a,
        const float* __restrict__ Wl_s, const float* __restrict__ WrD,
        const float* __restrict__ WrA, const float* __restrict__ WrS,
        const float* __restrict__ bD, const float* __restrict__ bA,
        const float* __restrict__ bS, float* __restrict__ out, int N) {
    __shared__ unsigned int Bp[128 * 64];
    __shared__ __align__(16) float At[8][512];
    int wave = threadIdx.x >> 6, lane = threadIdx.x & 63;
    int base = (blockIdx.x * 8 + wave) * 4;
    float acc[4][2] = {{0.f,0.f},{0.f,0.f},{0.f,0.f},{0.f,0.f}};
    // phase 1: re (post -> user), 1.75
    stage_B(Wl_d, Bp, threadIdx.x);
    __syncthreads();
    gather_rows(xp, rp_re, col_re, 1.75f, base, N, lane, At[wave]);
    kloop_acc(At[wave], Bp, lane, acc);
    __syncthreads();
    // phase 2: fb (post -> user), 0.7
    stage_B(Wl_a, Bp, threadIdx.x);
    __syncthreads();
    gather_rows(xp, rp_fb, col_fb, 0.7f, base, N, lane, At[wave]);
    kloop_acc(At[wave], Bp, lane, acc);
    __syncthreads();
    // phase 3: soc (user -> user), 0.3
    stage_B(Wl_s, Bp, threadIdx.x);
    __syncthreads();
    gather_rows(xu, rp_soc, col_soc, 0.3f, base, N, lane, At[wave]);
    kloop_acc(At[wave], Bp, lane, acc);
    __syncthreads();
    // phase 4: dense xu @ combined Wr
    stage_B_comb(WrD, WrA, WrS, Bp, threadIdx.x);
    __syncthreads();
    load_rows(xu, base, N, lane, At[wave]);
    kloop_acc(At[wave], Bp, lane, acc);
    // epilogue
    float bc0 = 1.75f*bD[lane]    + 0.7f*bA[lane]    + 0.3f*bS[lane];
    float bc1 = 1.75f*bD[lane+64] + 0.7f*bA[lane+64] + 0.3f*bS[lane+64];
#pragma unroll
    for (int i = 0; i < 4; ++i) {
        int row = base + i;
        if (row < N) {
            out[(size_t)row * DD + lane]      = fmaxf(acc[i][0] + bc0, 0.f);
            out[(size_t)row * DD + lane + 64] = fmaxf(acc[i][1] + bc1, 0.f);
        }
    }
}

// out_post = relu(csr_mean(xu) @ Wl + xP @ Wr + b)  (R16 verbatim)
__global__ __launch_bounds__(512) void post_final_kernel(
        const float* __restrict__ xu, const int* __restrict__ rp,
        const int* __restrict__ col, const float* __restrict__ xp,
        const float* __restrict__ Wl, const float* __restrict__ Wr,
        const float* __restrict__ bias, float* __restrict__ out, int N) {
    __shared__ unsigned int Bp[128 * 64];
    __shared__ __align__(16) float At[8][512];
    int wave = threadIdx.x >> 6, lane = threadIdx.x & 63;
    int base = (blockIdx.x * 8 + wave) * 4;
    float acc[4][2] = {{0.f,0.f},{0.f,0.f},{0.f,0.f},{0.f,0.f}};
    stage_B(Wl, Bp, threadIdx.x);
    __syncthreads();
    gather_rows(xu, rp, col, 1.0f, base, N, lane, At[wave]);
    kloop_acc(At[wave], Bp, lane, acc);
    __syncthreads();
    stage_B(Wr, Bp, threadIdx.x);
    __syncthreads();
    load_rows(xp, base, N, lane, At[wave]);
    kloop_acc(At[wave], Bp, lane, acc);
    float b0 = bias[lane], b1 = bias[lane + 64];
#pragma unroll
    for (int i = 0; i < 4; ++i) {
        int row = base + i;
        if (row < N) {
            out[(size_t)row * DD + lane]      = fmaxf(acc[i][0] + b0, 0.f);
            out[(size_t)row * DD + lane + 64] = fmaxf(acc[i][1] + b1, 0.f);
        }
    }
}

// ------------------------------------------------------------------ launch --
extern "C" void kernel_launch(void* const* d_in, const int* in_sizes, int n_in,
                              void* d_out, int out_size, void* d_ws, size_t ws_size,
                              hipStream_t stream) {
    const float* x_user  = (const float*)d_in[0];
    const float* x_post  = (const float*)d_in[1];
    const int*   re_src  = (const int*)d_in[2];
    const int*   re_dst  = (const int*)d_in[3];
    const int*   fb_src  = (const int*)d_in[4];
    const int*   fb_dst  = (const int*)d_in[5];
    const int*   soc_src = (const int*)d_in[6];
    const int*   soc_dst = (const int*)d_in[7];
    const int*   eng_src = (const int*)d_in[8];
    const int*   eng_dst = (const int*)d_in[9];
    const float* Wl_d = (const float*)d_in[10];
    const float* bl_d = (const float*)d_in[11];
    const float* Wr_d = (const float*)d_in[12];
    const float* Wl_a = (const float*)d_in[13];
    const float* bl_a = (const float*)d_in[14];
    const float* Wr_a = (const float*)d_in[15];
    const float* Wl_s = (const float*)d_in[16];
    const float* bl_s = (const float*)d_in[17];
    const float* Wr_s = (const float*)d_in[18];
    const float* Wl_p = (const float*)d_in[19];
    const float* bl_p = (const float*)d_in[20];
    const float* Wr_p = (const float*)d_in[21];

    const int E_re  = in_sizes[2];
    const int E_fb  = in_sizes[4];
    const int E_soc = in_sizes[6];
    const int E_eng = in_sizes[8];

    int* ib = (int*)d_ws;
    int* rp_re   = ib;
    int* rp_fb   = rp_re  + (N_USER + 1);
    int* rp_soc  = rp_fb  + (N_USER + 1);
    int* rp_post = rp_soc + (N_USER + 1);
    int* wcur    = rp_post + (N_POST + 1);
    int* psum    = wcur + N_POST;
    int* col_re  = psum + 64;
    int* col_fb  = col_re + E_re;
    int* col_soc = col_fb + E_fb;
    int* col_post= col_soc + E_soc;

    float* out_user = (float*)d_out;
    float* out_post = out_user + (size_t)N_USER * DD;

    const int gU = (N_USER + 31) / 32;   // 3125 blocks * 32 rows
    const int gP = (N_POST + 31) / 32;   // 6250 blocks * 32 rows

    auto build_csr = [&](const int* src, const int* dst, int E, int Ndst,
                         int* rp, int* col) {
        hipMemsetAsync(rp, 0, (Ndst + 1) * sizeof(int), stream);
        hipMemsetAsync(wcur, 0, Ndst * sizeof(int), stream);
        csr_hist<<<1024, 256, 0, stream>>>(dst, E, rp);
        int nb = (Ndst + SCCH - 1) / SCCH;          // <= 49
        scan_partial<<<nb, SCB, 0, stream>>>(rp, Ndst, psum);
        scan_psum<<<1, 1024, 0, stream>>>(psum, nb);
        scan_final<<<nb, SCB, 0, stream>>>(rp, Ndst, psum, E);
        csr_fill<<<1024, 256, 0, stream>>>(src, dst, E, rp, wcur, col);
    };

    build_csr(re_src,  re_dst,  E_re,  N_USER, rp_re,   col_re);
    build_csr(fb_src,  fb_dst,  E_fb,  N_USER, rp_fb,   col_fb);
    build_csr(soc_src, soc_dst, E_soc, N_USER, rp_soc,  col_soc);
    build_csr(eng_src, eng_dst, E_eng, N_POST, rp_post, col_post);

    user_fused_kernel<<<gU, 512, 0, stream>>>(
        x_user, x_post, rp_re, col_re, rp_fb, col_fb, rp_soc, col_soc,
        Wl_d, Wl_a, Wl_s, Wr_d, Wr_a, Wr_s, bl_d, bl_a, bl_s,
        out_user, N_USER);

    post_final_kernel<<<gP, 512, 0, stream>>>(x_user, rp_post, col_post, x_post,
                                              Wl_p, Wr_p, bl_p, out_post, N_POST);
}

// Round 19
// 1591.055 us; speedup vs baseline: 1.7020x; 1.0917x over previous
//
#include <hip/hip_runtime.h>

// WeightedRGCN on MI355X. Round 19: R18 (1737us, proven) + two cuts:
//  1. CSR build fused across relations: 1 memset + hist_all + fill_all
//     (per-relation wcur; R18-proven scan kernels kept verbatim per relation)
//  2. user_fused + post_final merged into ONE launch (block-uniform branch,
//     proven bodies, user blocks first) -> tail overlap.
// No numerics change: predict absmax 0.0625.
//
// ws (ints): rp_re/fb/soc (100001 ea), rp_post (200001), wcur_re/fb/soc
// (100000 ea), wcur_post (200000), psum (256), col_re/fb/soc/post (E ea).

#define N_USER 100000
#define N_POST 200000
#define DD 128
#define GU 3125            // (N_USER+31)/32
#define GP 6250            // (N_POST+31)/32

__device__ __forceinline__ unsigned int pack2_bf16(float lo, float hi) {
    unsigned int ulo, uhi;
    __builtin_memcpy(&ulo, &lo, 4);
    __builtin_memcpy(&uhi, &hi, 4);
    unsigned int rlo = (ulo + 0x7fffu + ((ulo >> 16) & 1u)) >> 16;   // RNE
    unsigned int rhi = (uhi + 0x7fffu + ((uhi >> 16) & 1u)) >> 16;
    return (rlo & 0xffffu) | (rhi << 16);
}
__device__ __forceinline__ float bf16_lo(unsigned int u) {
    unsigned int t = u << 16; float f; __builtin_memcpy(&f, &t, 4); return f;
}
__device__ __forceinline__ float bf16_hi(unsigned int u) {
    unsigned int t = u & 0xffff0000u; float f; __builtin_memcpy(&f, &t, 4); return f;
}

// -------------------------------------------------------------- CSR build ---
// all 4 relations' histograms in one kernel
__global__ __launch_bounds__(256) void hist_all(
        const int* __restrict__ d0, int e0, int* __restrict__ c0,
        const int* __restrict__ d1, int e1, int* __restrict__ c1,
        const int* __restrict__ d2, int e2, int* __restrict__ c2,
        const int* __restrict__ d3, int e3, int* __restrict__ c3) {
    int i = blockIdx.x * 256 + threadIdx.x;
    int stride = gridDim.x * 256;
    int b1 = e0, b2 = e0 + e1, b3 = e0 + e1 + e2, tot = b3 + e3;
    for (int t = i; t < tot; t += stride) {
        if (t < b1)      atomicAdd(&c0[d0[t]], 1);
        else if (t < b2) atomicAdd(&c1[d1[t - b1]], 1);
        else if (t < b3) atomicAdd(&c2[d2[t - b2]], 1);
        else             atomicAdd(&c3[d3[t - b3]], 1);
    }
}

// all 4 relations' fills in one kernel (per-relation wcur)
__global__ __launch_bounds__(256) void fill_all(
        const int* __restrict__ s0, const int* __restrict__ d0, int e0,
        const int* __restrict__ r0, int* __restrict__ w0, int* __restrict__ o0,
        const int* __restrict__ s1, const int* __restrict__ d1, int e1,
        const int* __restrict__ r1, int* __restrict__ w1, int* __restrict__ o1,
        const int* __restrict__ s2, const int* __restrict__ d2, int e2,
        const int* __restrict__ r2, int* __restrict__ w2, int* __restrict__ o2,
        const int* __restrict__ s3, const int* __restrict__ d3, int e3,
        const int* __restrict__ r3, int* __restrict__ w3, int* __restrict__ o3) {
    int i = blockIdx.x * 256 + threadIdx.x;
    int stride = gridDim.x * 256;
    int b1 = e0, b2 = e0 + e1, b3 = e0 + e1 + e2, tot = b3 + e3;
    for (int t = i; t < tot; t += stride) {
        if (t < b1)      { int e = t;      int d = d0[e]; o0[r0[d] + atomicAdd(&w0[d], 1)] = s0[e]; }
        else if (t < b2) { int e = t - b1; int d = d1[e]; o1[r1[d] + atomicAdd(&w1[d], 1)] = s1[e]; }
        else if (t < b3) { int e = t - b2; int d = d2[e]; o2[r2[d] + atomicAdd(&w2[d], 1)] = s2[e]; }
        else             { int e = t - b3; int d = d3[e]; o3[r3[d] + atomicAdd(&w3[d], 1)] = s3[e]; }
    }
}

// two-level exclusive scan (R18-proven, verbatim)
#define SCB 256
#define SCE 16
#define SCCH (SCB * SCE)   // 4096 elems per block

__global__ __launch_bounds__(SCB) void scan_partial(
        const int* __restrict__ a, int N, int* __restrict__ psum) {
    __shared__ int red[SCB];
    int b = blockIdx.x, tid = threadIdx.x;
    int i0 = b * SCCH + tid * SCE;
    int s = 0;
#pragma unroll
    for (int j = 0; j < SCE; ++j) { int i = i0 + j; if (i < N) s += a[i]; }
    red[tid] = s;
    __syncthreads();
    for (int off = SCB / 2; off > 0; off >>= 1) {
        if (tid < off) red[tid] += red[tid + off];
        __syncthreads();
    }
    if (tid == 0) psum[b] = red[0];
}

__global__ __launch_bounds__(1024) void scan_psum(int* __restrict__ psum, int nb) {
    __shared__ int t[1024];
    int tid = threadIdx.x;
    int v = (tid < nb) ? psum[tid] : 0;
    t[tid] = v;
    __syncthreads();
    for (int off = 1; off < 1024; off <<= 1) {
        int u = (tid >= off) ? t[tid - off] : 0;
        __syncthreads();
        t[tid] += u;
        __syncthreads();
    }
    if (tid < nb) psum[tid] = t[tid] - v;   // exclusive
}

__global__ __launch_bounds__(SCB) void scan_final(
        int* __restrict__ a, int N, const int* __restrict__ psum, int E) {
    __shared__ int red[SCB];
    int b = blockIdx.x, tid = threadIdx.x;
    int i0 = b * SCCH + tid * SCE;
    int v[SCE];
    int s = 0;
#pragma unroll
    for (int j = 0; j < SCE; ++j) { int i = i0 + j; v[j] = (i < N) ? a[i] : 0; s += v[j]; }
    red[tid] = s;
    __syncthreads();
    for (int off = 1; off < SCB; off <<= 1) {   // inclusive Hillis-Steele
        int u = (tid >= off) ? red[tid - off] : 0;
        __syncthreads();
        red[tid] += u;
        __syncthreads();
    }
    int run = psum[b] + red[tid] - s;           // exclusive prefix for thread
#pragma unroll
    for (int j = 0; j < SCE; ++j) { int i = i0 + j; if (i < N) a[i] = run; run += v[j]; }
    if (b == 0 && tid == 0) a[N] = E;
}

// ------------------------------------------------- GEMM pieces (R18 proven) --
__device__ __forceinline__ void stage_B(const float* __restrict__ B,
                                        unsigned int* Bp, int tid) {
    for (int i = tid; i < 128 * 64; i += 512) {
        int k = i >> 6, j = i & 63;
        Bp[i] = pack2_bf16(B[k * 128 + j], B[k * 128 + j + 64]);
    }
}
__device__ __forceinline__ void stage_B_comb(const float* __restrict__ W0,
                                             const float* __restrict__ W1,
                                             const float* __restrict__ W2,
                                             unsigned int* Bp, int tid) {
    for (int i = tid; i < 128 * 64; i += 512) {
        int k = i >> 6, j = i & 63;
        float lo = 1.75f * W0[k*128+j]    + 0.7f * W1[k*128+j]    + 0.3f * W2[k*128+j];
        float hi = 1.75f * W0[k*128+j+64] + 0.7f * W1[k*128+j+64] + 0.3f * W2[k*128+j+64];
        Bp[i] = pack2_bf16(lo, hi);
    }
}

__device__ __forceinline__ void load_rows(const float* __restrict__ A,
                                          int base, int N, int lane, float* at) {
#pragma unroll
    for (int i = 0; i < 4; ++i) {
        int row = base + i;
        float a0 = 0.f, a1 = 0.f;
        if (row < N) {
            a0 = A[(size_t)row * DD + lane];
            a1 = A[(size_t)row * DD + 64 + lane];
        }
        at[lane * 4 + i] = a0;
        at[(lane + 64) * 4 + i] = a1;
    }
}

// R16-verified interleaved gather (float2 -> slots 2*lane, 2*lane+1)
__device__ __forceinline__ void gather_rows(const float* __restrict__ x,
                                            const int* __restrict__ rp,
                                            const int* __restrict__ col, float scale,
                                            int base, int N, int lane, float* at) {
    int s0[4], dg[4];
    int maxd = 0;
#pragma unroll
    for (int i = 0; i < 4; ++i) {
        int row = base + i;
        int e0 = (row < N) ? rp[row] : 0;
        int e1 = (row < N) ? rp[row + 1] : 0;
        s0[i] = e0;
        dg[i] = e1 - e0;
        maxd = max(maxd, dg[i]);
    }
    float a0[4] = {0.f, 0.f, 0.f, 0.f};
    float a1[4] = {0.f, 0.f, 0.f, 0.f};
#pragma unroll 2
    for (int d = 0; d < maxd; ++d) {
#pragma unroll
        for (int i = 0; i < 4; ++i) {
            if (d < dg[i]) {
                const float2* xr = (const float2*)(x + (size_t)col[s0[i] + d] * DD);
                float2 v = xr[lane];
                a0[i] += v.x;
                a1[i] += v.y;
            }
        }
    }
#pragma unroll
    for (int i = 0; i < 4; ++i) {
        float inv = scale / fmaxf((float)dg[i], 1.0f);
        at[(2 * lane) * 4 + i]     = a0[i] * inv;   // feature 2*lane
        at[(2 * lane + 1) * 4 + i] = a1[i] * inv;   // feature 2*lane+1
    }
}

// unroll 4 (NOT full): full unroll spills under the 128-VGPR cap (R5 35GB).
__device__ __forceinline__ void kloop_acc(const float* at, const unsigned int* Bp,
                                          int lane, float acc[4][2]) {
#pragma unroll 4
    for (int k = 0; k < 128; ++k) {
        float4 x = *reinterpret_cast<const float4*>(at + k * 4);
        unsigned int u = Bp[k * 64 + lane];
        float b0 = bf16_lo(u), b1 = bf16_hi(u);
        acc[0][0] = fmaf(x.x, b0, acc[0][0]); acc[0][1] = fmaf(x.x, b1, acc[0][1]);
        acc[1][0] = fmaf(x.y, b0, acc[1][0]); acc[1][1] = fmaf(x.y, b1, acc[1][1]);
        acc[2][0] = fmaf(x.z, b0, acc[2][0]); acc[2][1] = fmaf(x.z, b1, acc[2][1]);
        acc[3][0] = fmaf(x.w, b0, acc[3][0]); acc[3][1] = fmaf(x.w, b1, acc[3][1]);
    }
}

// --------------------------------------------------------- fused main bodies
__device__ void user_body(
        int blk, const float* __restrict__ xu, const float* __restrict__ xp,
        const int* __restrict__ rp_re, const int* __restrict__ col_re,
        const int* __restrict__ rp_fb, const int* __restrict__ col_fb,
        const int* __restrict__ rp_soc, const int* __restrict__ col_soc,
        const float* __restrict__ Wl_d, const float* __restrict__ Wl_a,
        const float* __restrict__ Wl_s, const float* __restrict__ WrD,
        const float* __restrict__ WrA, const float* __restrict__ WrS,
        const float* __restrict__ bD, const float* __restrict__ bA,
        const float* __restrict__ bS, float* __restrict__ out,
        unsigned int* Bp, float (*At)[512]) {
    int wave = threadIdx.x >> 6, lane = threadIdx.x & 63;
    int base = (blk * 8 + wave) * 4;
    float acc[4][2] = {{0.f,0.f},{0.f,0.f},{0.f,0.f},{0.f,0.f}};
    // phase 1: re (post -> user), 1.75
    stage_B(Wl_d, Bp, threadIdx.x);
    __syncthreads();
    gather_rows(xp, rp_re, col_re, 1.75f, base, N_USER, lane, At[wave]);
    kloop_acc(At[wave], Bp, lane, acc);
    __syncthreads();
    // phase 2: fb (post -> user), 0.7
    stage_B(Wl_a, Bp, threadIdx.x);
    __syncthreads();
    gather_rows(xp, rp_fb, col_fb, 0.7f, base, N_USER, lane, At[wave]);
    kloop_acc(At[wave], Bp, lane, acc);
    __syncthreads();
    // phase 3: soc (user -> user), 0.3
    stage_B(Wl_s, Bp, threadIdx.x);
    __syncthreads();
    gather_rows(xu, rp_soc, col_soc, 0.3f, base, N_USER, lane, At[wave]);
    kloop_acc(At[wave], Bp, lane, acc);
    __syncthreads();
    // phase 4: dense xu @ combined Wr
    stage_B_comb(WrD, WrA, WrS, Bp, threadIdx.x);
    __syncthreads();
    load_rows(xu, base, N_USER, lane, At[wave]);
    kloop_acc(At[wave], Bp, lane, acc);
    // epilogue
    float bc0 = 1.75f*bD[lane]    + 0.7f*bA[lane]    + 0.3f*bS[lane];
    float bc1 = 1.75f*bD[lane+64] + 0.7f*bA[lane+64] + 0.3f*bS[lane+64];
#pragma unroll
    for (int i = 0; i < 4; ++i) {
        int row = base + i;
        if (row < N_USER) {
            out[(size_t)row * DD + lane]      = fmaxf(acc[i][0] + bc0, 0.f);
            out[(size_t)row * DD + lane + 64] = fmaxf(acc[i][1] + bc1, 0.f);
        }
    }
}

__device__ void post_body(
        int blk, const float* __restrict__ xu, const int* __restrict__ rp,
        const int* __restrict__ col, const float* __restrict__ xp,
        const float* __restrict__ Wl, const float* __restrict__ Wr,
        const float* __restrict__ bias, float* __restrict__ out,
        unsigned int* Bp, float (*At)[512]) {
    int wave = threadIdx.x >> 6, lane = threadIdx.x & 63;
    int base = (blk * 8 + wave) * 4;
    float acc[4][2] = {{0.f,0.f},{0.f,0.f},{0.f,0.f},{0.f,0.f}};
    stage_B(Wl, Bp, threadIdx.x);
    __syncthreads();
    gather_rows(xu, rp, col, 1.0f, base, N_POST, lane, At[wave]);
    kloop_acc(At[wave], Bp, lane, acc);
    __syncthreads();
    stage_B(Wr, Bp, threadIdx.x);
    __syncthreads();
    load_rows(xp, base, N_POST, lane, At[wave]);
    kloop_acc(At[wave], Bp, lane, acc);
    float b0 = bias[lane], b1 = bias[lane + 64];
#pragma unroll
    for (int i = 0; i < 4; ++i) {
        int row = base + i;
        if (row < N_POST) {
            out[(size_t)row * DD + lane]      = fmaxf(acc[i][0] + b0, 0.f);
            out[(size_t)row * DD + lane + 64] = fmaxf(acc[i][1] + b1, 0.f);
        }
    }
}

// user blocks [0, GU), post blocks [GU, GU+GP)
__global__ __launch_bounds__(512) void main_fused_kernel(
        const float* __restrict__ xu, const float* __restrict__ xp,
        const int* __restrict__ rp_re, const int* __restrict__ col_re,
        const int* __restrict__ rp_fb, const int* __restrict__ col_fb,
        const int* __restrict__ rp_soc, const int* __restrict__ col_soc,
        const int* __restrict__ rp_post, const int* __restrict__ col_post,
        const float* __restrict__ Wl_d, const float* __restrict__ Wl_a,
        const float* __restrict__ Wl_s, const float* __restrict__ WrD,
        const float* __restrict__ WrA, const float* __restrict__ WrS,
        const float* __restrict__ bD, const float* __restrict__ bA,
        const float* __restrict__ bS, const float* __restrict__ Wl_p,
        const float* __restrict__ Wr_p, const float* __restrict__ bl_p,
        float* __restrict__ out_user, float* __restrict__ out_post) {
    __shared__ unsigned int Bp[128 * 64];
    __shared__ __align__(16) float At[8][512];
    if (blockIdx.x < GU) {
        user_body(blockIdx.x, xu, xp, rp_re, col_re, rp_fb, col_fb,
                  rp_soc, col_soc, Wl_d, Wl_a, Wl_s, WrD, WrA, WrS,
                  bD, bA, bS, out_user, Bp, At);
    } else {
        post_body(blockIdx.x - GU, xu, rp_post, col_post, xp,
                  Wl_p, Wr_p, bl_p, out_post, Bp, At);
    }
}

// ------------------------------------------------------------------ launch --
extern "C" void kernel_launch(void* const* d_in, const int* in_sizes, int n_in,
                              void* d_out, int out_size, void* d_ws, size_t ws_size,
                              hipStream_t stream) {
    const float* x_user  = (const float*)d_in[0];
    const float* x_post  = (const float*)d_in[1];
    const int*   re_src  = (const int*)d_in[2];
    const int*   re_dst  = (const int*)d_in[3];
    const int*   fb_src  = (const int*)d_in[4];
    const int*   fb_dst  = (const int*)d_in[5];
    const int*   soc_src = (const int*)d_in[6];
    const int*   soc_dst = (const int*)d_in[7];
    const int*   eng_src = (const int*)d_in[8];
    const int*   eng_dst = (const int*)d_in[9];
    const float* Wl_d = (const float*)d_in[10];
    const float* bl_d = (const float*)d_in[11];
    const float* Wr_d = (const float*)d_in[12];
    const float* Wl_a = (const float*)d_in[13];
    const float* bl_a = (const float*)d_in[14];
    const float* Wr_a = (const float*)d_in[15];
    const float* Wl_s = (const float*)d_in[16];
    const float* bl_s = (const float*)d_in[17];
    const float* Wr_s = (const float*)d_in[18];
    const float* Wl_p = (const float*)d_in[19];
    const float* bl_p = (const float*)d_in[20];
    const float* Wr_p = (const float*)d_in[21];

    const int E_re  = in_sizes[2];
    const int E_fb  = in_sizes[4];
    const int E_soc = in_sizes[6];
    const int E_eng = in_sizes[8];

    int* ib = (int*)d_ws;
    int* rp_re    = ib;
    int* rp_fb    = rp_re   + (N_USER + 1);
    int* rp_soc   = rp_fb   + (N_USER + 1);
    int* rp_post  = rp_soc  + (N_USER + 1);
    int* wcur_re  = rp_post + (N_POST + 1);
    int* wcur_fb  = wcur_re + N_USER;
    int* wcur_soc = wcur_fb + N_USER;
    int* wcur_post= wcur_soc+ N_USER;
    int* psum     = wcur_post + N_POST;      // 4 x 64 slices
    int* col_re   = psum + 256;
    int* col_fb   = col_re  + E_re;
    int* col_soc  = col_fb  + E_fb;
    int* col_post = col_soc + E_soc;

    float* out_user = (float*)d_out;
    float* out_post = out_user + (size_t)N_USER * DD;

    // one memset over rp + wcur + psum (contiguous)
    size_t zero_ints = (size_t)(N_USER + 1) * 3 + (N_POST + 1)
                     + (size_t)N_USER * 3 + N_POST + 256;
    hipMemsetAsync(rp_re, 0, zero_ints * sizeof(int), stream);

    // fused histograms
    hist_all<<<2048, 256, 0, stream>>>(re_dst, E_re, rp_re,
                                       fb_dst, E_fb, rp_fb,
                                       soc_dst, E_soc, rp_soc,
                                       eng_dst, E_eng, rp_post);

    // per-relation scans (R18-proven kernels, own psum slices)
    {
        int nbU = (N_USER + SCCH - 1) / SCCH;   // 25
        int nbP = (N_POST + SCCH - 1) / SCCH;   // 49
        scan_partial<<<nbU, SCB, 0, stream>>>(rp_re, N_USER, psum + 0);
        scan_psum<<<1, 1024, 0, stream>>>(psum + 0, nbU);
        scan_final<<<nbU, SCB, 0, stream>>>(rp_re, N_USER, psum + 0, E_re);
        scan_partial<<<nbU, SCB, 0, stream>>>(rp_fb, N_USER, psum + 64);
        scan_psum<<<1, 1024, 0, stream>>>(psum + 64, nbU);
        scan_final<<<nbU, SCB, 0, stream>>>(rp_fb, N_USER, psum + 64, E_fb);
        scan_partial<<<nbU, SCB, 0, stream>>>(rp_soc, N_USER, psum + 128);
        scan_psum<<<1, 1024, 0, stream>>>(psum + 128, nbU);
        scan_final<<<nbU, SCB, 0, stream>>>(rp_soc, N_USER, psum + 128, E_soc);
        scan_partial<<<nbP, SCB, 0, stream>>>(rp_post, N_POST, psum + 192);
        scan_psum<<<1, 1024, 0, stream>>>(psum + 192, nbP);
        scan_final<<<nbP, SCB, 0, stream>>>(rp_post, N_POST, psum + 192, E_eng);
    }

    // fused fills
    fill_all<<<2048, 256, 0, stream>>>(
        re_src,  re_dst,  E_re,  rp_re,   wcur_re,   col_re,
        fb_src,  fb_dst,  E_fb,  rp_fb,   wcur_fb,   col_fb,
        soc_src, soc_dst, E_soc, rp_soc,  wcur_soc,  col_soc,
        eng_src, eng_dst, E_eng, rp_post, wcur_post, col_post);

    // merged main kernel: user blocks first (heavier), then post
    main_fused_kernel<<<GU + GP, 512, 0, stream>>>(
        x_user, x_post, rp_re, col_re, rp_fb, col_fb, rp_soc, col_soc,
        rp_post, col_post, Wl_d, Wl_a, Wl_s, Wr_d, Wr_a, Wr_s,
        bl_d, bl_a, bl_s, Wl_p, Wr_p, bl_p, out_user, out_post);
}

// Round 20
// 1485.362 us; speedup vs baseline: 1.8231x; 1.0712x over previous
//
#include <hip/hip_runtime.h>

// WeightedRGCN on MI355X. Round 20: R19 (1591us) + two disjoint changes:
//  1. bf16 A-tile: LDS 48KB->40KB => 4 blocks/CU (occupancy 68%->~100%),
//     kloop reads 8B/k. A rounded to bf16 (absmax ~0.09-0.13 < 0.214).
//  2. scans fused: 12 launches -> 3 (segmented, same proven bodies).
// Failure localization: big absmax => scan fusion; ~0.2 absmax => bf16 A.
//
// ws (ints): rp_re/fb/soc (100001 ea), rp_post (200001), wcur x4, psum(256),
// col_re/fb/soc/post.

#define N_USER 100000
#define N_POST 200000
#define DD 128
#define GU 3125            // (N_USER+31)/32
#define GP 6250            // (N_POST+31)/32

__device__ __forceinline__ unsigned int pack2_bf16(float lo, float hi) {
    unsigned int ulo, uhi;
    __builtin_memcpy(&ulo, &lo, 4);
    __builtin_memcpy(&uhi, &hi, 4);
    unsigned int rlo = (ulo + 0x7fffu + ((ulo >> 16) & 1u)) >> 16;   // RNE
    unsigned int rhi = (uhi + 0x7fffu + ((uhi >> 16) & 1u)) >> 16;
    return (rlo & 0xffffu) | (rhi << 16);
}
__device__ __forceinline__ float bf16_lo(unsigned int u) {
    unsigned int t = u << 16; float f; __builtin_memcpy(&f, &t, 4); return f;
}
__device__ __forceinline__ float bf16_hi(unsigned int u) {
    unsigned int t = u & 0xffff0000u; float f; __builtin_memcpy(&f, &t, 4); return f;
}

// -------------------------------------------------------------- CSR build ---
__global__ __launch_bounds__(256) void hist_all(
        const int* __restrict__ d0, int e0, int* __restrict__ c0,
        const int* __restrict__ d1, int e1, int* __restrict__ c1,
        const int* __restrict__ d2, int e2, int* __restrict__ c2,
        const int* __restrict__ d3, int e3, int* __restrict__ c3) {
    int i = blockIdx.x * 256 + threadIdx.x;
    int stride = gridDim.x * 256;
    int b1 = e0, b2 = e0 + e1, b3 = e0 + e1 + e2, tot = b3 + e3;
    for (int t = i; t < tot; t += stride) {
        if (t < b1)      atomicAdd(&c0[d0[t]], 1);
        else if (t < b2) atomicAdd(&c1[d1[t - b1]], 1);
        else if (t < b3) atomicAdd(&c2[d2[t - b2]], 1);
        else             atomicAdd(&c3[d3[t - b3]], 1);
    }
}

__global__ __launch_bounds__(256) void fill_all(
        const int* __restrict__ s0, const int* __restrict__ d0, int e0,
        const int* __restrict__ r0, int* __restrict__ w0, int* __restrict__ o0,
        const int* __restrict__ s1, const int* __restrict__ d1, int e1,
        const int* __restrict__ r1, int* __restrict__ w1, int* __restrict__ o1,
        const int* __restrict__ s2, const int* __restrict__ d2, int e2,
        const int* __restrict__ r2, int* __restrict__ w2, int* __restrict__ o2,
        const int* __restrict__ s3, const int* __restrict__ d3, int e3,
        const int* __restrict__ r3, int* __restrict__ w3, int* __restrict__ o3) {
    int i = blockIdx.x * 256 + threadIdx.x;
    int stride = gridDim.x * 256;
    int b1 = e0, b2 = e0 + e1, b3 = e0 + e1 + e2, tot = b3 + e3;
    for (int t = i; t < tot; t += stride) {
        if (t < b1)      { int e = t;      int d = d0[e]; o0[r0[d] + atomicAdd(&w0[d], 1)] = s0[e]; }
        else if (t < b2) { int e = t - b1; int d = d1[e]; o1[r1[d] + atomicAdd(&w1[d], 1)] = s1[e]; }
        else if (t < b3) { int e = t - b2; int d = d2[e]; o2[r2[d] + atomicAdd(&w2[d], 1)] = s2[e]; }
        else             { int e = t - b3; int d = d3[e]; o3[r3[d] + atomicAdd(&w3[d], 1)] = s3[e]; }
    }
}

// segmented two-level scan: 4 relations in 3 launches (bodies = R18-proven)
#define SCB 256
#define SCE 16
#define SCCH (SCB * SCE)   // 4096
#define NBU 25             // ceil(100000/4096)
#define NBP 49             // ceil(200000/4096)

__device__ __forceinline__ void seg_map(int b, int* rp0, int* rp1, int* rp2,
                                        int* rp3, int* psum,
                                        int** a, int* N, int** ps, int* lb) {
    if (b < NBU)            { *a = rp0; *N = N_USER; *ps = psum;       *lb = b; }
    else if (b < 2 * NBU)   { *a = rp1; *N = N_USER; *ps = psum + 64;  *lb = b - NBU; }
    else if (b < 3 * NBU)   { *a = rp2; *N = N_USER; *ps = psum + 128; *lb = b - 2 * NBU; }
    else                    { *a = rp3; *N = N_POST; *ps = psum + 192; *lb = b - 3 * NBU; }
}

__global__ __launch_bounds__(SCB) void scan_partial_all(
        int* rp0, int* rp1, int* rp2, int* rp3, int* psum) {
    int* a; int N; int* ps; int lb;
    seg_map(blockIdx.x, rp0, rp1, rp2, rp3, psum, &a, &N, &ps, &lb);
    __shared__ int red[SCB];
    int tid = threadIdx.x;
    int i0 = lb * SCCH + tid * SCE;
    int s = 0;
#pragma unroll
    for (int j = 0; j < SCE; ++j) { int i = i0 + j; if (i < N) s += a[i]; }
    red[tid] = s;
    __syncthreads();
    for (int off = SCB / 2; off > 0; off >>= 1) {
        if (tid < off) red[tid] += red[tid + off];
        __syncthreads();
    }
    if (tid == 0) ps[lb] = red[0];
}

__global__ __launch_bounds__(1024) void scan_psum_all(int* __restrict__ psum) {
    __shared__ int t[1024];
    int tid = threadIdx.x;
    int nb = (blockIdx.x == 3) ? NBP : NBU;
    int* ps = psum + blockIdx.x * 64;
    int v = (tid < nb) ? ps[tid] : 0;
    t[tid] = v;
    __syncthreads();
    for (int off = 1; off < 1024; off <<= 1) {
        int u = (tid >= off) ? t[tid - off] : 0;
        __syncthreads();
        t[tid] += u;
        __syncthreads();
    }
    if (tid < nb) ps[tid] = t[tid] - v;   // exclusive
}

__global__ __launch_bounds__(SCB) void scan_final_all(
        int* rp0, int* rp1, int* rp2, int* rp3, int* psum,
        int E0, int E1, int E2, int E3) {
    int* a; int N; int* ps; int lb;
    seg_map(blockIdx.x, rp0, rp1, rp2, rp3, psum, &a, &N, &ps, &lb);
    int E = (blockIdx.x < NBU) ? E0 : (blockIdx.x < 2*NBU) ? E1
          : (blockIdx.x < 3*NBU) ? E2 : E3;
    __shared__ int red[SCB];
    int tid = threadIdx.x;
    int i0 = lb * SCCH + tid * SCE;
    int v[SCE];
    int s = 0;
#pragma unroll
    for (int j = 0; j < SCE; ++j) { int i = i0 + j; v[j] = (i < N) ? a[i] : 0; s += v[j]; }
    red[tid] = s;
    __syncthreads();
    for (int off = 1; off < SCB; off <<= 1) {   // inclusive Hillis-Steele
        int u = (tid >= off) ? red[tid - off] : 0;
        __syncthreads();
        red[tid] += u;
        __syncthreads();
    }
    int run = ps[lb] + red[tid] - s;
#pragma unroll
    for (int j = 0; j < SCE; ++j) { int i = i0 + j; if (i < N) a[i] = run; run += v[j]; }
    if (lb == 0 && tid == 0) a[N] = E;
}

// ------------------------------------------------------------ GEMM pieces ---
__device__ __forceinline__ void stage_B(const float* __restrict__ B,
                                        unsigned int* Bp, int tid) {
    for (int i = tid; i < 128 * 64; i += 512) {
        int k = i >> 6, j = i & 63;
        Bp[i] = pack2_bf16(B[k * 128 + j], B[k * 128 + j + 64]);
    }
}
__device__ __forceinline__ void stage_B_comb(const float* __restrict__ W0,
                                             const float* __restrict__ W1,
                                             const float* __restrict__ W2,
                                             unsigned int* Bp, int tid) {
    for (int i = tid; i < 128 * 64; i += 512) {
        int k = i >> 6, j = i & 63;
        float lo = 1.75f * W0[k*128+j]    + 0.7f * W1[k*128+j]    + 0.3f * W2[k*128+j];
        float hi = 1.75f * W0[k*128+j+64] + 0.7f * W1[k*128+j+64] + 0.3f * W2[k*128+j+64];
        Bp[i] = pack2_bf16(lo, hi);
    }
}

// dense 4 rows -> bf16 A-tile words: atw[k*2]=(r0,r1), atw[k*2+1]=(r2,r3)
__device__ __forceinline__ void load_rows(const float* __restrict__ A,
                                          int base, int N, int lane,
                                          unsigned int* atw) {
    float v0[4], v1[4];
#pragma unroll
    for (int i = 0; i < 4; ++i) {
        int row = base + i;
        v0[i] = 0.f; v1[i] = 0.f;
        if (row < N) {
            v0[i] = A[(size_t)row * DD + lane];
            v1[i] = A[(size_t)row * DD + 64 + lane];
        }
    }
    atw[lane * 2]            = pack2_bf16(v0[0], v0[1]);
    atw[lane * 2 + 1]        = pack2_bf16(v0[2], v0[3]);
    atw[(lane + 64) * 2]     = pack2_bf16(v1[0], v1[1]);
    atw[(lane + 64) * 2 + 1] = pack2_bf16(v1[2], v1[3]);
}

// CSR-mean 4 rows (R16-proven interleave), bf16 A-tile store:
// features 2*lane (a0) and 2*lane+1 (a1) -> words 4*lane .. 4*lane+3
__device__ __forceinline__ void gather_rows(const float* __restrict__ x,
                                            const int* __restrict__ rp,
                                            const int* __restrict__ col, float scale,
                                            int base, int N, int lane,
                                            unsigned int* atw) {
    int s0[4], dg[4];
    int maxd = 0;
#pragma unroll
    for (int i = 0; i < 4; ++i) {
        int row = base + i;
        int e0 = (row < N) ? rp[row] : 0;
        int e1 = (row < N) ? rp[row + 1] : 0;
        s0[i] = e0;
        dg[i] = e1 - e0;
        maxd = max(maxd, dg[i]);
    }
    float a0[4] = {0.f, 0.f, 0.f, 0.f};
    float a1[4] = {0.f, 0.f, 0.f, 0.f};
#pragma unroll 2
    for (int d = 0; d < maxd; ++d) {
#pragma unroll
        for (int i = 0; i < 4; ++i) {
            if (d < dg[i]) {
                const float2* xr = (const float2*)(x + (size_t)col[s0[i] + d] * DD);
                float2 v = xr[lane];
                a0[i] += v.x;
                a1[i] += v.y;
            }
        }
    }
    float inv[4];
#pragma unroll
    for (int i = 0; i < 4; ++i) inv[i] = scale / fmaxf((float)dg[i], 1.0f);
    uint4 w;
    w.x = pack2_bf16(a0[0] * inv[0], a0[1] * inv[1]);   // feat 2*lane, rows 0,1
    w.y = pack2_bf16(a0[2] * inv[2], a0[3] * inv[3]);   // feat 2*lane, rows 2,3
    w.z = pack2_bf16(a1[0] * inv[0], a1[1] * inv[1]);   // feat 2*lane+1, rows 0,1
    w.w = pack2_bf16(a1[2] * inv[2], a1[3] * inv[3]);   // feat 2*lane+1, rows 2,3
    *reinterpret_cast<uint4*>(atw + 4 * lane) = w;
}

// unroll 4 (NOT full): full unroll spills under the 128-VGPR cap (R5 35GB).
__device__ __forceinline__ void kloop_acc(const unsigned int* atw,
                                          const unsigned int* Bp,
                                          int lane, float acc[4][2]) {
#pragma unroll 4
    for (int k = 0; k < 128; ++k) {
        uint2 w = *reinterpret_cast<const uint2*>(atw + k * 2);
        float x0 = bf16_lo(w.x), x1 = bf16_hi(w.x);
        float x2 = bf16_lo(w.y), x3 = bf16_hi(w.y);
        unsigned int u = Bp[k * 64 + lane];
        float b0 = bf16_lo(u), b1 = bf16_hi(u);
        acc[0][0] = fmaf(x0, b0, acc[0][0]); acc[0][1] = fmaf(x0, b1, acc[0][1]);
        acc[1][0] = fmaf(x1, b0, acc[1][0]); acc[1][1] = fmaf(x1, b1, acc[1][1]);
        acc[2][0] = fmaf(x2, b0, acc[2][0]); acc[2][1] = fmaf(x2, b1, acc[2][1]);
        acc[3][0] = fmaf(x3, b0, acc[3][0]); acc[3][1] = fmaf(x3, b1, acc[3][1]);
    }
}

// --------------------------------------------------------- fused main bodies
__device__ void user_body(
        int blk, const float* __restrict__ xu, const float* __restrict__ xp,
        const int* __restrict__ rp_re, const int* __restrict__ col_re,
        const int* __restrict__ rp_fb, const int* __restrict__ col_fb,
        const int* __restrict__ rp_soc, const int* __restrict__ col_soc,
        const float* __restrict__ Wl_d, const float* __restrict__ Wl_a,
        const float* __restrict__ Wl_s, const float* __restrict__ WrD,
        const float* __restrict__ WrA, const float* __restrict__ WrS,
        const float* __restrict__ bD, const float* __restrict__ bA,
        const float* __restrict__ bS, float* __restrict__ out,
        unsigned int* Bp, unsigned int (*Atw)[256]) {
    int wave = threadIdx.x >> 6, lane = threadIdx.x & 63;
    int base = (blk * 8 + wave) * 4;
    float acc[4][2] = {{0.f,0.f},{0.f,0.f},{0.f,0.f},{0.f,0.f}};
    stage_B(Wl_d, Bp, threadIdx.x);
    __syncthreads();
    gather_rows(xp, rp_re, col_re, 1.75f, base, N_USER, lane, Atw[wave]);
    kloop_acc(Atw[wave], Bp, lane, acc);
    __syncthreads();
    stage_B(Wl_a, Bp, threadIdx.x);
    __syncthreads();
    gather_rows(xp, rp_fb, col_fb, 0.7f, base, N_USER, lane, Atw[wave]);
    kloop_acc(Atw[wave], Bp, lane, acc);
    __syncthreads();
    stage_B(Wl_s, Bp, threadIdx.x);
    __syncthreads();
    gather_rows(xu, rp_soc, col_soc, 0.3f, base, N_USER, lane, Atw[wave]);
    kloop_acc(Atw[wave], Bp, lane, acc);
    __syncthreads();
    stage_B_comb(WrD, WrA, WrS, Bp, threadIdx.x);
    __syncthreads();
    load_rows(xu, base, N_USER, lane, Atw[wave]);
    kloop_acc(Atw[wave], Bp, lane, acc);
    float bc0 = 1.75f*bD[lane]    + 0.7f*bA[lane]    + 0.3f*bS[lane];
    float bc1 = 1.75f*bD[lane+64] + 0.7f*bA[lane+64] + 0.3f*bS[lane+64];
#pragma unroll
    for (int i = 0; i < 4; ++i) {
        int row = base + i;
        if (row < N_USER) {
            out[(size_t)row * DD + lane]      = fmaxf(acc[i][0] + bc0, 0.f);
            out[(size_t)row * DD + lane + 64] = fmaxf(acc[i][1] + bc1, 0.f);
        }
    }
}

__device__ void post_body(
        int blk, const float* __restrict__ xu, const int* __restrict__ rp,
        const int* __restrict__ col, const float* __restrict__ xp,
        const float* __restrict__ Wl, const float* __restrict__ Wr,
        const float* __restrict__ bias, float* __restrict__ out,
        unsigned int* Bp, unsigned int (*Atw)[256]) {
    int wave = threadIdx.x >> 6, lane = threadIdx.x & 63;
    int base = (blk * 8 + wave) * 4;
    float acc[4][2] = {{0.f,0.f},{0.f,0.f},{0.f,0.f},{0.f,0.f}};
    stage_B(Wl, Bp, threadIdx.x);
    __syncthreads();
    gather_rows(xu, rp, col, 1.0f, base, N_POST, lane, Atw[wave]);
    kloop_acc(Atw[wave], Bp, lane, acc);
    __syncthreads();
    stage_B(Wr, Bp, threadIdx.x);
    __syncthreads();
    load_rows(xp, base, N_POST, lane, Atw[wave]);
    kloop_acc(Atw[wave], Bp, lane, acc);
    float b0 = bias[lane], b1 = bias[lane + 64];
#pragma unroll
    for (int i = 0; i < 4; ++i) {
        int row = base + i;
        if (row < N_POST) {
            out[(size_t)row * DD + lane]      = fmaxf(acc[i][0] + b0, 0.f);
            out[(size_t)row * DD + lane + 64] = fmaxf(acc[i][1] + b1, 0.f);
        }
    }
}

// user blocks [0, GU), post blocks [GU, GU+GP)
__global__ __launch_bounds__(512) void main_fused_kernel(
        const float* __restrict__ xu, const float* __restrict__ xp,
        const int* __restrict__ rp_re, const int* __restrict__ col_re,
        const int* __restrict__ rp_fb, const int* __restrict__ col_fb,
        const int* __restrict__ rp_soc, const int* __restrict__ col_soc,
        const int* __restrict__ rp_post, const int* __restrict__ col_post,
        const float* __restrict__ Wl_d, const float* __restrict__ Wl_a,
        const float* __restrict__ Wl_s, const float* __restrict__ WrD,
        const float* __restrict__ WrA, const float* __restrict__ WrS,
        const float* __restrict__ bD, const float* __restrict__ bA,
        const float* __restrict__ bS, const float* __restrict__ Wl_p,
        const float* __restrict__ Wr_p, const float* __restrict__ bl_p,
        float* __restrict__ out_user, float* __restrict__ out_post) {
    __shared__ unsigned int Bp[128 * 64];        // 32 KB
    __shared__ unsigned int Atw[8][256];         // 8 KB -> total 40 KB, 4 blk/CU
    if (blockIdx.x < GU) {
        user_body(blockIdx.x, xu, xp, rp_re, col_re, rp_fb, col_fb,
                  rp_soc, col_soc, Wl_d, Wl_a, Wl_s, WrD, WrA, WrS,
                  bD, bA, bS, out_user, Bp, Atw);
    } else {
        post_body(blockIdx.x - GU, xu, rp_post, col_post, xp,
                  Wl_p, Wr_p, bl_p, out_post, Bp, Atw);
    }
}

// ------------------------------------------------------------------ launch --
extern "C" void kernel_launch(void* const* d_in, const int* in_sizes, int n_in,
                              void* d_out, int out_size, void* d_ws, size_t ws_size,
                              hipStream_t stream) {
    const float* x_user  = (const float*)d_in[0];
    const float* x_post  = (const float*)d_in[1];
    const int*   re_src  = (const int*)d_in[2];
    const int*   re_dst  = (const int*)d_in[3];
    const int*   fb_src  = (const int*)d_in[4];
    const int*   fb_dst  = (const int*)d_in[5];
    const int*   soc_src = (const int*)d_in[6];
    const int*   soc_dst = (const int*)d_in[7];
    const int*   eng_src = (const int*)d_in[8];
    const int*   eng_dst = (const int*)d_in[9];
    const float* Wl_d = (const float*)d_in[10];
    const float* bl_d = (const float*)d_in[11];
    const float* Wr_d = (const float*)d_in[12];
    const float* Wl_a = (const float*)d_in[13];
    const float* bl_a = (const float*)d_in[14];
    const float* Wr_a = (const float*)d_in[15];
    const float* Wl_s = (const float*)d_in[16];
    const float* bl_s = (const float*)d_in[17];
    const float* Wr_s = (const float*)d_in[18];
    const float* Wl_p = (const float*)d_in[19];
    const float* bl_p = (const float*)d_in[20];
    const float* Wr_p = (const float*)d_in[21];

    const int E_re  = in_sizes[2];
    const int E_fb  = in_sizes[4];
    const int E_soc = in_sizes[6];
    const int E_eng = in_sizes[8];

    int* ib = (int*)d_ws;
    int* rp_re    = ib;
    int* rp_fb    = rp_re   + (N_USER + 1);
    int* rp_soc   = rp_fb   + (N_USER + 1);
    int* rp_post  = rp_soc  + (N_USER + 1);
    int* wcur_re  = rp_post + (N_POST + 1);
    int* wcur_fb  = wcur_re + N_USER;
    int* wcur_soc = wcur_fb + N_USER;
    int* wcur_post= wcur_soc+ N_USER;
    int* psum     = wcur_post + N_POST;      // 4 x 64 slices
    int* col_re   = psum + 256;
    int* col_fb   = col_re  + E_re;
    int* col_soc  = col_fb  + E_fb;
    int* col_post = col_soc + E_soc;

    float* out_user = (float*)d_out;
    float* out_post = out_user + (size_t)N_USER * DD;

    // one memset over rp + wcur + psum (contiguous)
    size_t zero_ints = (size_t)(N_USER + 1) * 3 + (N_POST + 1)
                     + (size_t)N_USER * 3 + N_POST + 256;
    hipMemsetAsync(rp_re, 0, zero_ints * sizeof(int), stream);

    hist_all<<<2048, 256, 0, stream>>>(re_dst, E_re, rp_re,
                                       fb_dst, E_fb, rp_fb,
                                       soc_dst, E_soc, rp_soc,
                                       eng_dst, E_eng, rp_post);

    const int SC_BLOCKS_ALL = 3 * NBU + NBP;   // 124
    scan_partial_all<<<SC_BLOCKS_ALL, SCB, 0, stream>>>(rp_re, rp_fb, rp_soc,
                                                        rp_post, psum);
    scan_psum_all<<<4, 1024, 0, stream>>>(psum);
    scan_final_all<<<SC_BLOCKS_ALL, SCB, 0, stream>>>(rp_re, rp_fb, rp_soc,
                                                      rp_post, psum,
                                                      E_re, E_fb, E_soc, E_eng);

    fill_all<<<2048, 256, 0, stream>>>(
        re_src,  re_dst,  E_re,  rp_re,   wcur_re,   col_re,
        fb_src,  fb_dst,  E_fb,  rp_fb,   wcur_fb,   col_fb,
        soc_src, soc_dst, E_soc, rp_soc,  wcur_soc,  col_soc,
        eng_src, eng_dst, E_eng, rp_post, wcur_post, col_post);

    main_fused_kernel<<<GU + GP, 512, 0, stream>>>(
        x_user, x_post, rp_re, col_re, rp_fb, col_fb, rp_soc, col_soc,
        rp_post, col_post, Wl_d, Wl_a, Wl_s, Wr_d, Wr_a, Wr_s,
        bl_d, bl_a, bl_s, Wl_p, Wr_p, bl_p, out_user, out_post);
}